// Round 1
// baseline (4404.959 us; speedup 1.0000x reference)
//
#include <hip/hip_runtime.h>

// APPNP: h = MLP(feats); then 10x { h = 0.9 * D^-1/2 A D^-1/2 h + 0.1 * h0 }
// N=100000, E=1600000, D_IN=512, D_HID=256, D_OUT=64

#define ND 100000
#define DIN 512
#define DHID 256
#define DOUT 64

// ---- degree accumulation (float atomics into zeroed buffers) ----
__global__ __launch_bounds__(256) void deg_kernel(const int* __restrict__ src,
                                                  const int* __restrict__ dst,
                                                  float* __restrict__ outdeg,
                                                  float* __restrict__ indeg, int E) {
    int e = blockIdx.x * 256 + threadIdx.x;
    if (e < E) {
        atomicAdd(&outdeg[src[e]], 1.0f);
        atomicAdd(&indeg[dst[e]], 1.0f);
    }
}

// ---- deg -> deg^-1/2 (in place) ----
__global__ __launch_bounds__(256) void norm_kernel(float* __restrict__ a,
                                                   float* __restrict__ b, int n) {
    int i = blockIdx.x * 256 + threadIdx.x;
    if (i < n) {
        a[i] = 1.0f / sqrtf(fmaxf(a[i], 1.0f));
        b[i] = 1.0f / sqrtf(fmaxf(b[i], 1.0f));
    }
}

// ---- fused 2-layer MLP: h0 = relu(feats@W1+b1)@W2+b2 ; also copies to hA ----
// block = 256 threads, 16 rows per block. A-tile (16x512, 32KB) + hidden (16x256, 16KB) in LDS.
__global__ __launch_bounds__(256) void mlp_kernel(const float* __restrict__ feats,
                                                  const float* __restrict__ W1,
                                                  const float* __restrict__ b1,
                                                  const float* __restrict__ W2,
                                                  const float* __restrict__ b2,
                                                  float* __restrict__ h0,
                                                  float* __restrict__ hA) {
    __shared__ float a_lds[16 * DIN];   // 32 KB
    __shared__ float hid[16 * DHID];    // 16 KB
    const int tid = threadIdx.x;
    const int row0 = blockIdx.x * 16;

    // stage A tile (contiguous 8192 floats), coalesced float4
    const float* Ablk = feats + (size_t)row0 * DIN;
    for (int j = tid * 4; j < 16 * DIN; j += 256 * 4) {
        *(float4*)&a_lds[j] = *(const float4*)&Ablk[j];
    }
    __syncthreads();

    // phase 1: hidden[r][c] for c = tid (0..255), r = 0..15
    {
        float acc[16];
#pragma unroll
        for (int r = 0; r < 16; ++r) acc[r] = 0.0f;
        const int c = tid;
        for (int k = 0; k < DIN; k += 4) {
            float w0 = W1[(k + 0) * DHID + c];
            float w1 = W1[(k + 1) * DHID + c];
            float w2 = W1[(k + 2) * DHID + c];
            float w3 = W1[(k + 3) * DHID + c];
#pragma unroll
            for (int r = 0; r < 16; ++r) {
                float4 a4 = *(const float4*)&a_lds[r * DIN + k];   // wave-broadcast
                acc[r] = fmaf(a4.x, w0, acc[r]);
                acc[r] = fmaf(a4.y, w1, acc[r]);
                acc[r] = fmaf(a4.z, w2, acc[r]);
                acc[r] = fmaf(a4.w, w3, acc[r]);
            }
        }
        float bb = b1[c];
#pragma unroll
        for (int r = 0; r < 16; ++r) hid[r * DHID + c] = fmaxf(acc[r] + bb, 0.0f);
    }
    __syncthreads();

    // phase 2: out[r][c] for c = tid&63, r in 4-row group
    {
        const int c = tid & 63;
        const int r0 = (tid >> 6) * 4;
        float acc[4] = {0.f, 0.f, 0.f, 0.f};
        for (int k = 0; k < DHID; k += 4) {
            float w0 = W2[(k + 0) * DOUT + c];
            float w1 = W2[(k + 1) * DOUT + c];
            float w2 = W2[(k + 2) * DOUT + c];
            float w3 = W2[(k + 3) * DOUT + c];
#pragma unroll
            for (int r = 0; r < 4; ++r) {
                float4 h4 = *(const float4*)&hid[(r0 + r) * DHID + k];  // wave-broadcast
                acc[r] = fmaf(h4.x, w0, acc[r]);
                acc[r] = fmaf(h4.y, w1, acc[r]);
                acc[r] = fmaf(h4.z, w2, acc[r]);
                acc[r] = fmaf(h4.w, w3, acc[r]);
            }
        }
        float bb = b2[c];
#pragma unroll
        for (int r = 0; r < 4; ++r) {
            float v = acc[r] + bb;
            size_t idx = (size_t)(row0 + r0 + r) * DOUT + c;
            h0[idx] = v;
            hA[idx] = v;
        }
    }
}

// ---- one propagation scatter: agg[dst] += h[src] * src_norm[src] ----
// one 64-lane wave per edge, lane = feature index; 4 edges per 256-thread block
__global__ __launch_bounds__(256) void scatter_kernel(const float* __restrict__ h,
                                                      const float* __restrict__ src_norm,
                                                      const int* __restrict__ src,
                                                      const int* __restrict__ dst,
                                                      float* __restrict__ agg, int E) {
    int e = blockIdx.x * 4 + (threadIdx.x >> 6);
    int lane = threadIdx.x & 63;
    if (e < E) {
        int s = src[e];
        int d = dst[e];
        float v = h[(size_t)s * DOUT + lane] * src_norm[s];
        atomicAdd(&agg[(size_t)d * DOUT + lane], v);
    }
}

// ---- update: out = 0.9 * agg * dst_norm + 0.1 * h0 (float4-wide) ----
__global__ __launch_bounds__(256) void update_kernel(const float* __restrict__ agg,
                                                     const float* __restrict__ dst_norm,
                                                     const float* __restrict__ h0,
                                                     float* __restrict__ out, int n4) {
    int i = blockIdx.x * 256 + threadIdx.x;
    if (i < n4) {
        int node = i >> 4;   // 16 float4 per node (64 floats)
        float dn = dst_norm[node];
        float4 a = ((const float4*)agg)[i];
        float4 h = ((const float4*)h0)[i];
        float4 o;
        o.x = 0.9f * a.x * dn + 0.1f * h.x;
        o.y = 0.9f * a.y * dn + 0.1f * h.y;
        o.z = 0.9f * a.z * dn + 0.1f * h.z;
        o.w = 0.9f * a.w * dn + 0.1f * h.w;
        ((float4*)out)[i] = o;
    }
}

extern "C" void kernel_launch(void* const* d_in, const int* in_sizes, int n_in,
                              void* d_out, int out_size, void* d_ws, size_t ws_size,
                              hipStream_t stream) {
    const float* feats = (const float*)d_in[0];
    const int*   src   = (const int*)d_in[1];
    const int*   dst   = (const int*)d_in[2];
    const float* W1    = (const float*)d_in[3];
    const float* b1    = (const float*)d_in[4];
    const float* W2    = (const float*)d_in[5];
    const float* b2    = (const float*)d_in[6];
    float* out = (float*)d_out;

    const int N = in_sizes[0] / DIN;   // 100000
    const int E = in_sizes[1];         // 1600000

    // workspace carve-out (256B aligned)
    char* w = (char*)d_ws;
    auto alloc = [&](size_t bytes) {
        char* p = w;
        w += (bytes + 255) & ~(size_t)255;
        return p;
    };
    float* src_norm = (float*)alloc((size_t)N * 4);
    float* dst_norm = (float*)alloc((size_t)N * 4);
    float* h0 = (float*)alloc((size_t)N * DOUT * 4);
    float* A  = (float*)alloc((size_t)N * DOUT * 4);
    float* B  = (float*)alloc((size_t)N * DOUT * 4);

    // degrees -> norms
    hipMemsetAsync(src_norm, 0, (size_t)N * 4, stream);
    hipMemsetAsync(dst_norm, 0, (size_t)N * 4, stream);
    deg_kernel<<<(E + 255) / 256, 256, 0, stream>>>(src, dst, src_norm, dst_norm, E);
    norm_kernel<<<(N + 255) / 256, 256, 0, stream>>>(src_norm, dst_norm, N);

    // fused MLP -> h0 (and working copy A)
    mlp_kernel<<<N / 16, 256, 0, stream>>>(feats, W1, b1, W2, b2, h0, A);

    // K = 10 propagation steps
    float* cur = A;
    float* nxt = B;
    for (int it = 0; it < 10; ++it) {
        hipMemsetAsync(nxt, 0, (size_t)N * DOUT * 4, stream);
        scatter_kernel<<<(E + 3) / 4, 256, 0, stream>>>(cur, src_norm, src, dst, nxt, E);
        float* dst_buf = (it == 9) ? out : nxt;
        update_kernel<<<(N * 16 + 255) / 256, 256, 0, stream>>>(nxt, dst_norm, h0, dst_buf, N * 16);
        float* t = cur; cur = nxt; nxt = t;
    }
}

// Round 2
// 1537.943 us; speedup vs baseline: 2.8642x; 2.8642x over previous
//
#include <hip/hip_runtime.h>

// APPNP: h = MLP(feats); then 10x { h = 0.9 * D^-1/2 A D^-1/2 h + 0.1 * h0 }
// N=100000, E=1600000, D_IN=512, D_HID=256, D_OUT=64
// Round 2: CSR-by-dst gather-reduce (no atomics in the hot loop), fused update.

#define DIN 512
#define DHID 256
#define DOUT 64

// ---- integer degree counts ----
__global__ __launch_bounds__(256) void deg_kernel(const int* __restrict__ src,
                                                  const int* __restrict__ dst,
                                                  int* __restrict__ out_cnt,
                                                  int* __restrict__ in_cnt, int E) {
    int e = blockIdx.x * 256 + threadIdx.x;
    if (e < E) {
        atomicAdd(&out_cnt[src[e]], 1);
        atomicAdd(&in_cnt[dst[e]], 1);
    }
}

// ---- counts -> deg^-1/2 norms ----
__global__ __launch_bounds__(256) void norm_kernel(const int* __restrict__ out_cnt,
                                                   const int* __restrict__ in_cnt,
                                                   float* __restrict__ src_norm,
                                                   float* __restrict__ dst_norm, int n) {
    int i = blockIdx.x * 256 + threadIdx.x;
    if (i < n) {
        src_norm[i] = rsqrtf((float)max(out_cnt[i], 1));
        dst_norm[i] = rsqrtf((float)max(in_cnt[i], 1));
    }
}

// ---- exclusive scan, stage 1: per-256-chunk scan + chunk totals ----
__global__ __launch_bounds__(256) void scan_chunk(const int* __restrict__ cnt,
                                                  int* __restrict__ row_start,
                                                  int* __restrict__ partials, int n) {
    __shared__ int buf[256];
    int t = threadIdx.x;
    int i = blockIdx.x * 256 + t;
    int v = (i < n) ? cnt[i] : 0;
    buf[t] = v;
    __syncthreads();
    int val = v;
    for (int off = 1; off < 256; off <<= 1) {
        int add = (t >= off) ? buf[t - off] : 0;
        __syncthreads();
        val += add;
        buf[t] = val;
        __syncthreads();
    }
    if (i < n) row_start[i] = val - v;                 // exclusive within chunk
    if (t == 255) partials[blockIdx.x] = val;          // chunk total
}

// ---- exclusive scan, stage 2: scan the (<512) chunk totals in one block ----
__global__ __launch_bounds__(512) void scan_partials(int* __restrict__ partials, int nb) {
    __shared__ int buf[512];
    int t = threadIdx.x;
    int v = (t < nb) ? partials[t] : 0;
    buf[t] = v;
    __syncthreads();
    int val = v;
    for (int off = 1; off < 512; off <<= 1) {
        int add = (t >= off) ? buf[t - off] : 0;
        __syncthreads();
        val += add;
        buf[t] = val;
        __syncthreads();
    }
    // exclusive result
    int ex = (t == 0) ? 0 : buf[t - 1];
    __syncthreads();
    if (t < nb) partials[t] = ex;
}

// ---- exclusive scan, stage 3: add chunk offsets; set row_start[N]=E ----
__global__ __launch_bounds__(256) void scan_add(int* __restrict__ row_start,
                                                const int* __restrict__ partials,
                                                int n, int E) {
    int i = blockIdx.x * 256 + threadIdx.x;
    if (i < n) row_start[i] += partials[blockIdx.x];
    if (i == n) row_start[n] = E;
}

// ---- CSR fill: scatter edge src ids into dst-sorted order ----
__global__ __launch_bounds__(256) void fill_csr(const int* __restrict__ src,
                                                const int* __restrict__ dst,
                                                const int* __restrict__ row_start,
                                                int* __restrict__ cursor,
                                                int* __restrict__ csr_src, int E) {
    int e = blockIdx.x * 256 + threadIdx.x;
    if (e < E) {
        int d = dst[e];
        int pos = row_start[d] + atomicAdd(&cursor[d], 1);
        csr_src[pos] = src[e];
    }
}

// ---- fused propagation step: out = 0.9 * dst_norm * sum_{in-edges}(h[s]*src_norm[s]) + 0.1*h0
// one 64-lane wave per dst node; 4 edges in flight (16 lanes x float4 each)
__global__ __launch_bounds__(256) void agg_kernel(const float* __restrict__ h,
                                                  const float* __restrict__ src_norm,
                                                  const int* __restrict__ row_start,
                                                  const int* __restrict__ csr_src,
                                                  const float* __restrict__ dst_norm,
                                                  const float* __restrict__ h0,
                                                  float* __restrict__ out, int N) {
    int node = blockIdx.x * 4 + (threadIdx.x >> 6);
    if (node >= N) return;
    int lane = threadIdx.x & 63;
    int g  = lane >> 4;    // edge sub-group 0..3
    int fl = lane & 15;    // float4 feature index 0..15

    int beg = row_start[node];
    int end = row_start[node + 1];

    float4 acc = make_float4(0.f, 0.f, 0.f, 0.f);
    for (int i = beg; i < end; i += 4) {
        int idx = i + g;
        bool valid = idx < end;
        int s = valid ? csr_src[idx] : 0;
        float w = valid ? src_norm[s] : 0.0f;
        float4 v = ((const float4*)h)[(size_t)s * 16 + fl];
        acc.x = fmaf(v.x, w, acc.x);
        acc.y = fmaf(v.y, w, acc.y);
        acc.z = fmaf(v.z, w, acc.z);
        acc.w = fmaf(v.w, w, acc.w);
    }
    // reduce the 4 edge sub-groups (lanes with equal fl)
    acc.x += __shfl_xor(acc.x, 16); acc.y += __shfl_xor(acc.y, 16);
    acc.z += __shfl_xor(acc.z, 16); acc.w += __shfl_xor(acc.w, 16);
    acc.x += __shfl_xor(acc.x, 32); acc.y += __shfl_xor(acc.y, 32);
    acc.z += __shfl_xor(acc.z, 32); acc.w += __shfl_xor(acc.w, 32);

    if (g == 0) {
        float dn = dst_norm[node];
        float4 h4 = ((const float4*)h0)[(size_t)node * 16 + fl];
        float4 o;
        o.x = fmaf(0.9f * dn, acc.x, 0.1f * h4.x);
        o.y = fmaf(0.9f * dn, acc.y, 0.1f * h4.y);
        o.z = fmaf(0.9f * dn, acc.z, 0.1f * h4.z);
        o.w = fmaf(0.9f * dn, acc.w, 0.1f * h4.w);
        ((float4*)out)[(size_t)node * 16 + fl] = o;
    }
}

// ---- fused 2-layer MLP: h0 = relu(feats@W1+b1)@W2+b2 ----
__global__ __launch_bounds__(256) void mlp_kernel(const float* __restrict__ feats,
                                                  const float* __restrict__ W1,
                                                  const float* __restrict__ b1,
                                                  const float* __restrict__ W2,
                                                  const float* __restrict__ b2,
                                                  float* __restrict__ h0) {
    __shared__ float a_lds[16 * DIN];   // 32 KB
    __shared__ float hid[16 * DHID];    // 16 KB
    const int tid = threadIdx.x;
    const int row0 = blockIdx.x * 16;

    const float* Ablk = feats + (size_t)row0 * DIN;
    for (int j = tid * 4; j < 16 * DIN; j += 256 * 4) {
        *(float4*)&a_lds[j] = *(const float4*)&Ablk[j];
    }
    __syncthreads();

    {
        float acc[16];
#pragma unroll
        for (int r = 0; r < 16; ++r) acc[r] = 0.0f;
        const int c = tid;
        for (int k = 0; k < DIN; k += 4) {
            float w0 = W1[(k + 0) * DHID + c];
            float w1 = W1[(k + 1) * DHID + c];
            float w2 = W1[(k + 2) * DHID + c];
            float w3 = W1[(k + 3) * DHID + c];
#pragma unroll
            for (int r = 0; r < 16; ++r) {
                float4 a4 = *(const float4*)&a_lds[r * DIN + k];
                acc[r] = fmaf(a4.x, w0, acc[r]);
                acc[r] = fmaf(a4.y, w1, acc[r]);
                acc[r] = fmaf(a4.z, w2, acc[r]);
                acc[r] = fmaf(a4.w, w3, acc[r]);
            }
        }
        float bb = b1[c];
#pragma unroll
        for (int r = 0; r < 16; ++r) hid[r * DHID + c] = fmaxf(acc[r] + bb, 0.0f);
    }
    __syncthreads();

    {
        const int c = tid & 63;
        const int r0 = (tid >> 6) * 4;
        float acc[4] = {0.f, 0.f, 0.f, 0.f};
        for (int k = 0; k < DHID; k += 4) {
            float w0 = W2[(k + 0) * DOUT + c];
            float w1 = W2[(k + 1) * DOUT + c];
            float w2 = W2[(k + 2) * DOUT + c];
            float w3 = W2[(k + 3) * DOUT + c];
#pragma unroll
            for (int r = 0; r < 4; ++r) {
                float4 h4 = *(const float4*)&hid[(r0 + r) * DHID + k];
                acc[r] = fmaf(h4.x, w0, acc[r]);
                acc[r] = fmaf(h4.y, w1, acc[r]);
                acc[r] = fmaf(h4.z, w2, acc[r]);
                acc[r] = fmaf(h4.w, w3, acc[r]);
            }
        }
        float bb = b2[c];
#pragma unroll
        for (int r = 0; r < 4; ++r) {
            h0[(size_t)(row0 + r0 + r) * DOUT + c] = acc[r] + bb;
        }
    }
}

extern "C" void kernel_launch(void* const* d_in, const int* in_sizes, int n_in,
                              void* d_out, int out_size, void* d_ws, size_t ws_size,
                              hipStream_t stream) {
    const float* feats = (const float*)d_in[0];
    const int*   src   = (const int*)d_in[1];
    const int*   dst   = (const int*)d_in[2];
    const float* W1    = (const float*)d_in[3];
    const float* b1    = (const float*)d_in[4];
    const float* W2    = (const float*)d_in[5];
    const float* b2    = (const float*)d_in[6];
    float* out = (float*)d_out;

    const int N = in_sizes[0] / DIN;   // 100000
    const int E = in_sizes[1];         // 1600000
    const int NCHUNK = (N + 255) / 256;

    char* w = (char*)d_ws;
    auto alloc = [&](size_t bytes) {
        char* p = w;
        w += (bytes + 255) & ~(size_t)255;
        return p;
    };
    float* src_norm  = (float*)alloc((size_t)N * 4);
    float* dst_norm  = (float*)alloc((size_t)N * 4);
    float* h0        = (float*)alloc((size_t)N * DOUT * 4);
    float* A         = (float*)alloc((size_t)N * DOUT * 4);
    float* B         = (float*)alloc((size_t)N * DOUT * 4);
    int*   out_cnt   = (int*)alloc((size_t)N * 4);
    int*   in_cnt    = (int*)alloc((size_t)N * 4);
    int*   cursor    = (int*)alloc((size_t)N * 4);
    int*   row_start = (int*)alloc((size_t)(N + 1) * 4);
    int*   partials  = (int*)alloc((size_t)NCHUNK * 4);
    int*   csr_src   = (int*)alloc((size_t)E * 4);

    // ---- CSR build (once per call) ----
    hipMemsetAsync(out_cnt, 0, (size_t)N * 4, stream);
    hipMemsetAsync(in_cnt, 0, (size_t)N * 4, stream);
    hipMemsetAsync(cursor, 0, (size_t)N * 4, stream);
    deg_kernel<<<(E + 255) / 256, 256, 0, stream>>>(src, dst, out_cnt, in_cnt, E);
    norm_kernel<<<NCHUNK, 256, 0, stream>>>(out_cnt, in_cnt, src_norm, dst_norm, N);
    scan_chunk<<<NCHUNK, 256, 0, stream>>>(in_cnt, row_start, partials, N);
    scan_partials<<<1, 512, 0, stream>>>(partials, NCHUNK);
    scan_add<<<(N + 256) / 256, 256, 0, stream>>>(row_start, partials, N, E);
    fill_csr<<<(E + 255) / 256, 256, 0, stream>>>(src, dst, row_start, cursor, csr_src, E);

    // ---- MLP -> h0 ----
    mlp_kernel<<<N / 16, 256, 0, stream>>>(feats, W1, b1, W2, b2, h0);

    // ---- K = 10 propagation steps (gather-reduce, fused update) ----
    const float* cur = h0;
    float* nxt = A;
    float* other = B;
    for (int it = 0; it < 10; ++it) {
        float* dst_buf = (it == 9) ? out : nxt;
        agg_kernel<<<(N + 3) / 4, 256, 0, stream>>>(cur, src_norm, row_start, csr_src,
                                                    dst_norm, h0, dst_buf, N);
        cur = dst_buf;
        nxt = other;
        other = (float*)((cur == A) ? B : A);
        if (it == 0) { nxt = B; other = A; }  // after first iter: cur=A, next writes B
    }
}

// Round 3
// 1194.203 us; speedup vs baseline: 3.6886x; 1.2878x over previous
//
#include <hip/hip_runtime.h>

// APPNP: h = MLP(feats); then 10x { h = 0.9 * D^-1/2 A D^-1/2 h + 0.1 * h0 }
// N=100000, E=1600000, D_IN=512, D_HID=256, D_OUT=64
// Round 3: MFMA MLP with split-bf16 (hi/lo) 3-term compensation.

#define DIN 512
#define DHID 256
#define DOUT 64

typedef __attribute__((ext_vector_type(8))) short short8;
typedef __attribute__((ext_vector_type(4))) float f32x4;

__device__ __forceinline__ unsigned short f2bf(float f) {
    unsigned u = __float_as_uint(f);
    u += 0x7fffu + ((u >> 16) & 1u);
    return (unsigned short)(u >> 16);
}
__device__ __forceinline__ float bf2f(unsigned short h) {
    return __uint_as_float(((unsigned)h) << 16);
}

// ---- prep: W1/W2 -> transposed bf16 hi/lo staged layouts ----
// w1s: [kf=16][pl=2][n=256][k=32]   (k global = kf*32 + e), value = W1[k][n]
// w2s: [kfi=8][pl=2][n=64][k=32]    value = W2[k][n]
__global__ __launch_bounds__(256) void prep_w(const float* __restrict__ W1,
                                              const float* __restrict__ W2,
                                              unsigned short* __restrict__ w1s,
                                              unsigned short* __restrict__ w2s) {
    int i = blockIdx.x * 256 + threadIdx.x;
    const int NW1 = 16 * 2 * 256 * 32;
    if (i < NW1) {
        int e = i & 31;
        int n = (i >> 5) & 255;
        int pl = (i >> 13) & 1;
        int kf = i >> 14;
        float v = W1[(kf * 32 + e) * DHID + n];
        unsigned short hi = f2bf(v);
        w1s[i] = pl ? f2bf(v - bf2f(hi)) : hi;
    } else {
        int j = i - NW1;
        if (j < 8 * 2 * 64 * 32) {
            int e = j & 31;
            int n = (j >> 5) & 63;
            int pl = (j >> 11) & 1;
            int kf = j >> 12;
            float v = W2[(kf * 32 + e) * DOUT + n];
            unsigned short hi = f2bf(v);
            w2s[j] = pl ? f2bf(v - bf2f(hi)) : hi;
        }
    }
}

__device__ __forceinline__ void cvt_store(char* wr_base, float4 f0, float4 f1) {
    float fv[8] = {f0.x, f0.y, f0.z, f0.w, f1.x, f1.y, f1.z, f1.w};
    short8 hi8, lo8;
#pragma unroll
    for (int e = 0; e < 8; ++e) {
        unsigned short h = f2bf(fv[e]);
        hi8[e] = (short)h;
        lo8[e] = (short)f2bf(fv[e] - bf2f(h));
    }
    *((short8*)(wr_base)) = hi8;          // hi plane
    *((short8*)(wr_base + 4096)) = lo8;   // lo plane (+4 KB)
}

// ---- fused MFMA MLP: h0 = relu(feats@W1+b1)@W2+b2, split-bf16 3-term ----
// 256 thr = 4 waves. BM=64 rows/block. Phase1: wave w owns cols w*64..+63.
// A staged fp32->bf16 hi/lo in LDS (double buf, 2x8KB, XOR chunk swizzle).
// W frags read 16B/lane direct from L2 (prepped layout).
__global__ __launch_bounds__(256) void mlp_mfma(const float* __restrict__ feats,
                                                const unsigned short* __restrict__ w1s,
                                                const unsigned short* __restrict__ w2s,
                                                const float* __restrict__ b1,
                                                const float* __restrict__ b2,
                                                float* __restrict__ h0out, int N) {
    __shared__ char smem[32768];
    const int tid = threadIdx.x;
    const int w = tid >> 6, l = tid & 63, c = l & 15, g = l >> 4;
    const int row0 = blockIdx.x * 64;

    f32x4 acc[4][4];
#pragma unroll
    for (int a = 0; a < 4; ++a)
#pragma unroll
        for (int b = 0; b < 4; ++b) acc[a][b] = (f32x4)0.0f;

    // A-stage addressing: thread handles row=tid>>2, k-chunk (tid&3)*8
    const int s_row = tid >> 2;
    const int s_chunk = (tid & 3) ^ ((s_row >> 1) & 3);   // XOR swizzle
    const int arow = min(row0 + s_row, N - 1);
    const float* aptr = feats + (size_t)arow * DIN + (tid & 3) * 8;
    char* wr_off = smem + s_row * 64 + s_chunk * 16;      // + buf*8192 (+4096 lo)
    // a-frag read: row=mf*16+c, chunk g^((c>>1)&3)  (lane-const swizzle)
    const char* rd_base = smem + c * 64 + ((g ^ ((c >> 1) & 3)) << 4);

    // prologue: load + convert kf=0 into buf0
    float4 pf0 = *(const float4*)(aptr);
    float4 pf1 = *(const float4*)(aptr + 4);
    cvt_store(wr_off, pf0, pf1);

    // ---- phase 1: K loop (16 x 32) ----
    for (int kf = 0; kf < 16; ++kf) {
        __syncthreads();
        const int b = kf & 1;
        if (kf < 15) {   // prefetch next A chunk
            pf0 = *(const float4*)(aptr + (kf + 1) * 32);
            pf1 = *(const float4*)(aptr + (kf + 1) * 32 + 4);
        }
        const char* ab = rd_base + b * 8192;
        short8 ah[4], al[4];
#pragma unroll
        for (int mf = 0; mf < 4; ++mf) {
            ah[mf] = *(const short8*)(ab + mf * 1024);
            al[mf] = *(const short8*)(ab + 4096 + mf * 1024);
        }
        const unsigned short* wp = w1s + (size_t)kf * 16384;  // [pl][256][32]
#pragma unroll
        for (int nf = 0; nf < 4; ++nf) {
            int n = w * 64 + nf * 16 + c;
            short8 bh = *(const short8*)(wp + n * 32 + g * 8);
            short8 bl = *(const short8*)(wp + (256 + n) * 32 + g * 8);
#pragma unroll
            for (int mf = 0; mf < 4; ++mf) {
                acc[mf][nf] = __builtin_amdgcn_mfma_f32_16x16x32_bf16(ah[mf], bh, acc[mf][nf], 0, 0, 0);
                acc[mf][nf] = __builtin_amdgcn_mfma_f32_16x16x32_bf16(al[mf], bh, acc[mf][nf], 0, 0, 0);
                acc[mf][nf] = __builtin_amdgcn_mfma_f32_16x16x32_bf16(ah[mf], bl, acc[mf][nf], 0, 0, 0);
            }
        }
        if (kf < 15) cvt_store(wr_off + (1 - b) * 8192, pf0, pf1);
    }

    // bias + relu (col = w*64 + nf*16 + c)
#pragma unroll
    for (int nf = 0; nf < 4; ++nf) {
        float bb = b1[w * 64 + nf * 16 + c];
#pragma unroll
        for (int mf = 0; mf < 4; ++mf)
#pragma unroll
            for (int r = 0; r < 4; ++r)
                acc[mf][nf][r] = fmaxf(acc[mf][nf][r] + bb, 0.0f);
    }

    // ---- phase 2: GEMM2 over K=256 in two halves (H via LDS, hi/lo planes) ----
    f32x4 acc2[4];
#pragma unroll
    for (int q = 0; q < 4; ++q) acc2[q] = (f32x4)0.0f;

    for (int half = 0; half < 2; ++half) {
        __syncthreads();   // previous LDS contents free
        if ((w >> 1) == half) {   // waves owning cols of this k-half write H
#pragma unroll
            for (int mf = 0; mf < 4; ++mf)
#pragma unroll
                for (int nf = 0; nf < 4; ++nf) {
                    int klocal = (w & 1) * 64 + nf * 16 + c;
#pragma unroll
                    for (int r = 0; r < 4; ++r) {
                        int row = mf * 16 + g * 4 + r;
                        int byt = row * 256 + ((klocal * 2) ^ ((row & 7) << 4));
                        float v = acc[mf][nf][r];
                        unsigned short hh = f2bf(v);
                        *(unsigned short*)(smem + byt) = hh;
                        *(unsigned short*)(smem + 16384 + byt) = f2bf(v - bf2f(hh));
                    }
                }
        }
        __syncthreads();
        // GEMM2 partial: wave w does rows w*16..+15, all 64 out cols
#pragma unroll
        for (int kf2 = 0; kf2 < 4; ++kf2) {
            int row = w * 16 + c;
            int kl = kf2 * 32 + g * 8;
            int byt = row * 256 + ((kl * 2) ^ ((row & 7) << 4));
            short8 a2h = *(const short8*)(smem + byt);
            short8 a2l = *(const short8*)(smem + 16384 + byt);
            const unsigned short* w2p = w2s + (size_t)(half * 4 + kf2) * 4096;  // [pl][64][32]
#pragma unroll
            for (int nf2 = 0; nf2 < 4; ++nf2) {
                int n2 = nf2 * 16 + c;
                short8 b2h = *(const short8*)(w2p + n2 * 32 + g * 8);
                short8 b2l = *(const short8*)(w2p + (64 + n2) * 32 + g * 8);
                acc2[nf2] = __builtin_amdgcn_mfma_f32_16x16x32_bf16(a2h, b2h, acc2[nf2], 0, 0, 0);
                acc2[nf2] = __builtin_amdgcn_mfma_f32_16x16x32_bf16(a2l, b2h, acc2[nf2], 0, 0, 0);
                acc2[nf2] = __builtin_amdgcn_mfma_f32_16x16x32_bf16(a2h, b2l, acc2[nf2], 0, 0, 0);
            }
        }
    }

    // store h0
#pragma unroll
    for (int nf2 = 0; nf2 < 4; ++nf2) {
        int oc = nf2 * 16 + c;
        float bb = b2[oc];
#pragma unroll
        for (int r = 0; r < 4; ++r) {
            int row = row0 + w * 16 + g * 4 + r;
            if (row < N) h0out[(size_t)row * DOUT + oc] = acc2[nf2][r] + bb;
        }
    }
}

// ---- integer degree counts ----
__global__ __launch_bounds__(256) void deg_kernel(const int* __restrict__ src,
                                                  const int* __restrict__ dst,
                                                  int* __restrict__ out_cnt,
                                                  int* __restrict__ in_cnt, int E) {
    int e = blockIdx.x * 256 + threadIdx.x;
    if (e < E) {
        atomicAdd(&out_cnt[src[e]], 1);
        atomicAdd(&in_cnt[dst[e]], 1);
    }
}

// ---- counts -> deg^-1/2 norms ----
__global__ __launch_bounds__(256) void norm_kernel(const int* __restrict__ out_cnt,
                                                   const int* __restrict__ in_cnt,
                                                   float* __restrict__ src_norm,
                                                   float* __restrict__ dst_norm, int n) {
    int i = blockIdx.x * 256 + threadIdx.x;
    if (i < n) {
        src_norm[i] = rsqrtf((float)max(out_cnt[i], 1));
        dst_norm[i] = rsqrtf((float)max(in_cnt[i], 1));
    }
}

// ---- exclusive scan, stage 1 ----
__global__ __launch_bounds__(256) void scan_chunk(const int* __restrict__ cnt,
                                                  int* __restrict__ row_start,
                                                  int* __restrict__ partials, int n) {
    __shared__ int buf[256];
    int t = threadIdx.x;
    int i = blockIdx.x * 256 + t;
    int v = (i < n) ? cnt[i] : 0;
    buf[t] = v;
    __syncthreads();
    int val = v;
    for (int off = 1; off < 256; off <<= 1) {
        int add = (t >= off) ? buf[t - off] : 0;
        __syncthreads();
        val += add;
        buf[t] = val;
        __syncthreads();
    }
    if (i < n) row_start[i] = val - v;
    if (t == 255) partials[blockIdx.x] = val;
}

// ---- exclusive scan, stage 2 ----
__global__ __launch_bounds__(512) void scan_partials(int* __restrict__ partials, int nb) {
    __shared__ int buf[512];
    int t = threadIdx.x;
    int v = (t < nb) ? partials[t] : 0;
    buf[t] = v;
    __syncthreads();
    int val = v;
    for (int off = 1; off < 512; off <<= 1) {
        int add = (t >= off) ? buf[t - off] : 0;
        __syncthreads();
        val += add;
        buf[t] = val;
        __syncthreads();
    }
    int ex = (t == 0) ? 0 : buf[t - 1];
    __syncthreads();
    if (t < nb) partials[t] = ex;
}

// ---- exclusive scan, stage 3 ----
__global__ __launch_bounds__(256) void scan_add(int* __restrict__ row_start,
                                                const int* __restrict__ partials,
                                                int n, int E) {
    int i = blockIdx.x * 256 + threadIdx.x;
    if (i < n) row_start[i] += partials[blockIdx.x];
    if (i == n) row_start[n] = E;
}

// ---- CSR fill ----
__global__ __launch_bounds__(256) void fill_csr(const int* __restrict__ src,
                                                const int* __restrict__ dst,
                                                const int* __restrict__ row_start,
                                                int* __restrict__ cursor,
                                                int* __restrict__ csr_src, int E) {
    int e = blockIdx.x * 256 + threadIdx.x;
    if (e < E) {
        int d = dst[e];
        int pos = row_start[d] + atomicAdd(&cursor[d], 1);
        csr_src[pos] = src[e];
    }
}

// ---- fused propagation step ----
__global__ __launch_bounds__(256) void agg_kernel(const float* __restrict__ h,
                                                  const float* __restrict__ src_norm,
                                                  const int* __restrict__ row_start,
                                                  const int* __restrict__ csr_src,
                                                  const float* __restrict__ dst_norm,
                                                  const float* __restrict__ h0,
                                                  float* __restrict__ out, int N) {
    int node = blockIdx.x * 4 + (threadIdx.x >> 6);
    if (node >= N) return;
    int lane = threadIdx.x & 63;
    int g  = lane >> 4;
    int fl = lane & 15;

    int beg = row_start[node];
    int end = row_start[node + 1];

    float4 acc = make_float4(0.f, 0.f, 0.f, 0.f);
    for (int i = beg; i < end; i += 4) {
        int idx = i + g;
        bool valid = idx < end;
        int s = valid ? csr_src[idx] : 0;
        float w = valid ? src_norm[s] : 0.0f;
        float4 v = ((const float4*)h)[(size_t)s * 16 + fl];
        acc.x = fmaf(v.x, w, acc.x);
        acc.y = fmaf(v.y, w, acc.y);
        acc.z = fmaf(v.z, w, acc.z);
        acc.w = fmaf(v.w, w, acc.w);
    }
    acc.x += __shfl_xor(acc.x, 16); acc.y += __shfl_xor(acc.y, 16);
    acc.z += __shfl_xor(acc.z, 16); acc.w += __shfl_xor(acc.w, 16);
    acc.x += __shfl_xor(acc.x, 32); acc.y += __shfl_xor(acc.y, 32);
    acc.z += __shfl_xor(acc.z, 32); acc.w += __shfl_xor(acc.w, 32);

    if (g == 0) {
        float dn = dst_norm[node];
        float4 h4 = ((const float4*)h0)[(size_t)node * 16 + fl];
        float4 o;
        o.x = fmaf(0.9f * dn, acc.x, 0.1f * h4.x);
        o.y = fmaf(0.9f * dn, acc.y, 0.1f * h4.y);
        o.z = fmaf(0.9f * dn, acc.z, 0.1f * h4.z);
        o.w = fmaf(0.9f * dn, acc.w, 0.1f * h4.w);
        ((float4*)out)[(size_t)node * 16 + fl] = o;
    }
}

extern "C" void kernel_launch(void* const* d_in, const int* in_sizes, int n_in,
                              void* d_out, int out_size, void* d_ws, size_t ws_size,
                              hipStream_t stream) {
    const float* feats = (const float*)d_in[0];
    const int*   src   = (const int*)d_in[1];
    const int*   dst   = (const int*)d_in[2];
    const float* W1    = (const float*)d_in[3];
    const float* b1    = (const float*)d_in[4];
    const float* W2    = (const float*)d_in[5];
    const float* b2    = (const float*)d_in[6];
    float* out = (float*)d_out;

    const int N = in_sizes[0] / DIN;   // 100000
    const int E = in_sizes[1];         // 1600000
    const int NCHUNK = (N + 255) / 256;

    char* w = (char*)d_ws;
    auto alloc = [&](size_t bytes) {
        char* p = w;
        w += (bytes + 255) & ~(size_t)255;
        return p;
    };
    float* src_norm  = (float*)alloc((size_t)N * 4);
    float* dst_norm  = (float*)alloc((size_t)N * 4);
    float* h0        = (float*)alloc((size_t)N * DOUT * 4);
    float* A         = (float*)alloc((size_t)N * DOUT * 4);
    float* B         = (float*)alloc((size_t)N * DOUT * 4);
    int*   out_cnt   = (int*)alloc((size_t)N * 4);
    int*   in_cnt    = (int*)alloc((size_t)N * 4);
    int*   cursor    = (int*)alloc((size_t)N * 4);
    int*   row_start = (int*)alloc((size_t)(N + 1) * 4);
    int*   partials  = (int*)alloc((size_t)NCHUNK * 4);
    int*   csr_src   = (int*)alloc((size_t)E * 4);
    unsigned short* w1s = (unsigned short*)alloc((size_t)16 * 2 * 256 * 32 * 2);
    unsigned short* w2s = (unsigned short*)alloc((size_t)8 * 2 * 64 * 32 * 2);

    // ---- weight prep (bf16 hi/lo transposed stage) ----
    prep_w<<<(16 * 2 * 256 * 32 + 8 * 2 * 64 * 32 + 255) / 256, 256, 0, stream>>>(W1, W2, w1s, w2s);

    // ---- CSR build ----
    hipMemsetAsync(out_cnt, 0, (size_t)N * 4, stream);
    hipMemsetAsync(in_cnt, 0, (size_t)N * 4, stream);
    hipMemsetAsync(cursor, 0, (size_t)N * 4, stream);
    deg_kernel<<<(E + 255) / 256, 256, 0, stream>>>(src, dst, out_cnt, in_cnt, E);
    norm_kernel<<<NCHUNK, 256, 0, stream>>>(out_cnt, in_cnt, src_norm, dst_norm, N);
    scan_chunk<<<NCHUNK, 256, 0, stream>>>(in_cnt, row_start, partials, N);
    scan_partials<<<1, 512, 0, stream>>>(partials, NCHUNK);
    scan_add<<<(N + 256) / 256, 256, 0, stream>>>(row_start, partials, N, E);
    fill_csr<<<(E + 255) / 256, 256, 0, stream>>>(src, dst, row_start, cursor, csr_src, E);

    // ---- MFMA MLP -> h0 ----
    mlp_mfma<<<(N + 63) / 64, 256, 0, stream>>>(feats, w1s, w2s, b1, b2, h0, N);

    // ---- K = 10 propagation steps ----
    const float* cur = h0;
    float* nxt = A;
    float* other = B;
    for (int it = 0; it < 10; ++it) {
        float* dst_buf = (it == 9) ? out : nxt;
        agg_kernel<<<(N + 3) / 4, 256, 0, stream>>>(cur, src_norm, row_start, csr_src,
                                                    dst_norm, h0, dst_buf, N);
        cur = dst_buf;
        nxt = other;
        other = (float*)((cur == A) ? B : A);
        if (it == 0) { nxt = B; other = A; }
    }
}

// Round 4
// 950.297 us; speedup vs baseline: 4.6354x; 1.2567x over previous
//
#include <hip/hip_runtime.h>
#include <hip/hip_fp16.h>

// APPNP: h = MLP(feats); then 10x { h = 0.9 * D^-1/2 A D^-1/2 h + 0.1 * h0 }
// N=100000, E=1600000, D_IN=512, D_HID=256, D_OUT=64
// Round 4: barrier-free MFMA MLP (full A-tile LDS stage, 128KB) + fp16 h
// propagation buffers (halved gather bytes) + fused per-edge weights in CSR.

#define DIN 512
#define DHID 256
#define DOUT 64

typedef __attribute__((ext_vector_type(8))) short short8;
typedef __attribute__((ext_vector_type(4))) float f32x4;

__device__ __forceinline__ unsigned short f2bf(float f) {
    unsigned u = __float_as_uint(f);
    u += 0x7fffu + ((u >> 16) & 1u);
    return (unsigned short)(u >> 16);
}
__device__ __forceinline__ float bf2f(unsigned short h) {
    return __uint_as_float(((unsigned)h) << 16);
}
__device__ __forceinline__ void cvt8(const float4& f0, const float4& f1,
                                     short8& hi8, short8& lo8) {
    float fv[8] = {f0.x, f0.y, f0.z, f0.w, f1.x, f1.y, f1.z, f1.w};
#pragma unroll
    for (int e = 0; e < 8; ++e) {
        unsigned short h = f2bf(fv[e]);
        hi8[e] = (short)h;
        lo8[e] = (short)f2bf(fv[e] - bf2f(h));
    }
}

// ---- prep: W1/W2 -> transposed bf16 hi/lo staged layouts ----
// w1s: [kf=16][pl=2][n=256][k=32], value = W1[kf*32+k][n]
// w2s: [kf2=8][pl=2][n=64][k=32],  value = W2[kf2*32+k][n]
__global__ __launch_bounds__(256) void prep_w(const float* __restrict__ W1,
                                              const float* __restrict__ W2,
                                              unsigned short* __restrict__ w1s,
                                              unsigned short* __restrict__ w2s) {
    int i = blockIdx.x * 256 + threadIdx.x;
    const int NW1 = 16 * 2 * 256 * 32;
    if (i < NW1) {
        int e = i & 31;
        int n = (i >> 5) & 255;
        int pl = (i >> 13) & 1;
        int kf = i >> 14;
        float v = W1[(kf * 32 + e) * DHID + n];
        unsigned short hi = f2bf(v);
        w1s[i] = pl ? f2bf(v - bf2f(hi)) : hi;
    } else {
        int j = i - NW1;
        if (j < 8 * 2 * 64 * 32) {
            int e = j & 31;
            int n = (j >> 5) & 63;
            int pl = (j >> 11) & 1;
            int kf = j >> 12;
            float v = W2[(kf * 32 + e) * DOUT + n];
            unsigned short hi = f2bf(v);
            w2s[j] = pl ? f2bf(v - bf2f(hi)) : hi;
        }
    }
}

// ---- fused MFMA MLP, barrier-free K-loop ----
// 256 thr = 4 waves, BM=64 rows/block, 1 block/CU (128KB LDS).
// LDS: A hi [0,64K), A lo [64K,128K); reused for hidden hi [0,32K) lo [32K,64K).
__global__ __launch_bounds__(256, 1) void mlp_mfma(const float* __restrict__ feats,
                                                   const unsigned short* __restrict__ w1s,
                                                   const unsigned short* __restrict__ w2s,
                                                   const float* __restrict__ b1,
                                                   const float* __restrict__ b2,
                                                   float* __restrict__ h0out,
                                                   __half* __restrict__ hA, int N) {
    __shared__ char smem[131072];
    const int tid = threadIdx.x;
    const int w = tid >> 6, l = tid & 63, c = l & 15, g = l >> 4;
    const int row0 = blockIdx.x * 64;

    // ---- stage A: 64 x 512 fp32 -> bf16 hi/lo, XOR-swizzled, ONE barrier ----
    {
        const int srow = tid & 63;           // consecutive lanes = consecutive rows
        const int kc = (tid >> 6) * 128;     // k-chunk per wave
        const int arow = min(row0 + srow, N - 1);
        const float* ap = feats + (size_t)arow * DIN + kc;
        const int sw = (srow & 7) << 4;
#pragma unroll
        for (int j = 0; j < 16; ++j) {
            float4 f0 = *(const float4*)(ap + j * 8);
            float4 f1 = *(const float4*)(ap + j * 8 + 4);
            short8 hi8, lo8;
            cvt8(f0, f1, hi8, lo8);
            int byt = (srow * 1024 + (kc + j * 8) * 2) ^ sw;
            *(short8*)(smem + byt) = hi8;
            *(short8*)(smem + 65536 + byt) = lo8;
        }
    }
    __syncthreads();

    // ---- GEMM1: free-running K loop (16 x 32), no barriers ----
    f32x4 acc[4][4];
#pragma unroll
    for (int a = 0; a < 4; ++a)
#pragma unroll
        for (int b = 0; b < 4; ++b) acc[a][b] = (f32x4)0.0f;

    const int cxor = (c & 7) << 4;
    for (int kf = 0; kf < 16; ++kf) {
        short8 ah[4], al[4];
#pragma unroll
        for (int mf = 0; mf < 4; ++mf) {
            int byt = (((mf * 16 + c) * 1024) + kf * 64 + g * 16) ^ cxor;
            ah[mf] = *(const short8*)(smem + byt);
            al[mf] = *(const short8*)(smem + 65536 + byt);
        }
        const unsigned short* wp = w1s + (size_t)kf * 16384;
#pragma unroll
        for (int nf = 0; nf < 4; ++nf) {
            int n = w * 64 + nf * 16 + c;
            short8 bh = *(const short8*)(wp + n * 32 + g * 8);
            short8 bl = *(const short8*)(wp + (256 + n) * 32 + g * 8);
#pragma unroll
            for (int mf = 0; mf < 4; ++mf) {
                acc[mf][nf] = __builtin_amdgcn_mfma_f32_16x16x32_bf16(ah[mf], bh, acc[mf][nf], 0, 0, 0);
                acc[mf][nf] = __builtin_amdgcn_mfma_f32_16x16x32_bf16(al[mf], bh, acc[mf][nf], 0, 0, 0);
                acc[mf][nf] = __builtin_amdgcn_mfma_f32_16x16x32_bf16(ah[mf], bl, acc[mf][nf], 0, 0, 0);
            }
        }
    }

    // bias + relu
#pragma unroll
    for (int nf = 0; nf < 4; ++nf) {
        float bb = b1[w * 64 + nf * 16 + c];
#pragma unroll
        for (int mf = 0; mf < 4; ++mf)
#pragma unroll
            for (int r = 0; r < 4; ++r)
                acc[mf][nf][r] = fmaxf(acc[mf][nf][r] + bb, 0.0f);
    }

    // ---- hidden -> LDS (hi/lo, swizzled), reuse A region ----
    __syncthreads();   // all GEMM1 LDS reads done
#pragma unroll
    for (int mf = 0; mf < 4; ++mf)
#pragma unroll
        for (int nf = 0; nf < 4; ++nf) {
            int kl = w * 64 + nf * 16 + c;
#pragma unroll
            for (int r = 0; r < 4; ++r) {
                int row = mf * 16 + g * 4 + r;
                int byt = (row * 512 + kl * 2) ^ ((row & 7) << 4);
                float v = acc[mf][nf][r];
                unsigned short hh = f2bf(v);
                *(unsigned short*)(smem + byt) = hh;
                *(unsigned short*)(smem + 32768 + byt) = f2bf(v - bf2f(hh));
            }
        }
    __syncthreads();

    // ---- GEMM2: K=256, wave w computes rows w*16..+15, all 64 cols ----
    f32x4 acc2[4];
#pragma unroll
    for (int q = 0; q < 4; ++q) acc2[q] = (f32x4)0.0f;

    for (int kf2 = 0; kf2 < 8; ++kf2) {
        int row = w * 16 + c;
        int byt = (row * 512 + (kf2 * 32 + g * 8) * 2) ^ ((row & 7) << 4);
        short8 a2h = *(const short8*)(smem + byt);
        short8 a2l = *(const short8*)(smem + 32768 + byt);
        const unsigned short* w2p = w2s + (size_t)kf2 * 4096;
#pragma unroll
        for (int nf2 = 0; nf2 < 4; ++nf2) {
            int n2 = nf2 * 16 + c;
            short8 b2h = *(const short8*)(w2p + n2 * 32 + g * 8);
            short8 b2l = *(const short8*)(w2p + (64 + n2) * 32 + g * 8);
            acc2[nf2] = __builtin_amdgcn_mfma_f32_16x16x32_bf16(a2h, b2h, acc2[nf2], 0, 0, 0);
            acc2[nf2] = __builtin_amdgcn_mfma_f32_16x16x32_bf16(a2l, b2h, acc2[nf2], 0, 0, 0);
            acc2[nf2] = __builtin_amdgcn_mfma_f32_16x16x32_bf16(a2h, b2l, acc2[nf2], 0, 0, 0);
        }
    }

    // ---- store h0 (fp32) + hA (fp16 working copy) ----
#pragma unroll
    for (int nf2 = 0; nf2 < 4; ++nf2) {
        int oc = nf2 * 16 + c;
        float bb = b2[oc];
#pragma unroll
        for (int r = 0; r < 4; ++r) {
            int row = row0 + w * 16 + g * 4 + r;
            if (row < N) {
                float v = acc2[nf2][r] + bb;
                h0out[(size_t)row * DOUT + oc] = v;
                hA[(size_t)row * DOUT + oc] = __float2half_rn(v);
            }
        }
    }
}

// ---- integer degree counts ----
__global__ __launch_bounds__(256) void deg_kernel(const int* __restrict__ src,
                                                  const int* __restrict__ dst,
                                                  int* __restrict__ out_cnt,
                                                  int* __restrict__ in_cnt, int E) {
    int e = blockIdx.x * 256 + threadIdx.x;
    if (e < E) {
        atomicAdd(&out_cnt[src[e]], 1);
        atomicAdd(&in_cnt[dst[e]], 1);
    }
}

// ---- counts -> deg^-1/2 norms ----
__global__ __launch_bounds__(256) void norm_kernel(const int* __restrict__ out_cnt,
                                                   const int* __restrict__ in_cnt,
                                                   float* __restrict__ src_norm,
                                                   float* __restrict__ dst_norm, int n) {
    int i = blockIdx.x * 256 + threadIdx.x;
    if (i < n) {
        src_norm[i] = rsqrtf((float)max(out_cnt[i], 1));
        dst_norm[i] = rsqrtf((float)max(in_cnt[i], 1));
    }
}

// ---- exclusive scan, stage 1 ----
__global__ __launch_bounds__(256) void scan_chunk(const int* __restrict__ cnt,
                                                  int* __restrict__ row_start,
                                                  int* __restrict__ partials, int n) {
    __shared__ int buf[256];
    int t = threadIdx.x;
    int i = blockIdx.x * 256 + t;
    int v = (i < n) ? cnt[i] : 0;
    buf[t] = v;
    __syncthreads();
    int val = v;
    for (int off = 1; off < 256; off <<= 1) {
        int add = (t >= off) ? buf[t - off] : 0;
        __syncthreads();
        val += add;
        buf[t] = val;
        __syncthreads();
    }
    if (i < n) row_start[i] = val - v;
    if (t == 255) partials[blockIdx.x] = val;
}

// ---- exclusive scan, stage 2 ----
__global__ __launch_bounds__(512) void scan_partials(int* __restrict__ partials, int nb) {
    __shared__ int buf[512];
    int t = threadIdx.x;
    int v = (t < nb) ? partials[t] : 0;
    buf[t] = v;
    __syncthreads();
    int val = v;
    for (int off = 1; off < 512; off <<= 1) {
        int add = (t >= off) ? buf[t - off] : 0;
        __syncthreads();
        val += add;
        buf[t] = val;
        __syncthreads();
    }
    int ex = (t == 0) ? 0 : buf[t - 1];
    __syncthreads();
    if (t < nb) partials[t] = ex;
}

// ---- exclusive scan, stage 3 ----
__global__ __launch_bounds__(256) void scan_add(int* __restrict__ row_start,
                                                const int* __restrict__ partials,
                                                int n, int E) {
    int i = blockIdx.x * 256 + threadIdx.x;
    if (i < n) row_start[i] += partials[blockIdx.x];
    if (i == n) row_start[n] = E;
}

// ---- CSR fill with fused per-edge weight: csr[pos] = (src, src_norm[src]) ----
__global__ __launch_bounds__(256) void fill_csr(const int* __restrict__ src,
                                                const int* __restrict__ dst,
                                                const int* __restrict__ row_start,
                                                const float* __restrict__ src_norm,
                                                int* __restrict__ cursor,
                                                int2* __restrict__ csr, int E) {
    int e = blockIdx.x * 256 + threadIdx.x;
    if (e < E) {
        int s = src[e];
        int d = dst[e];
        int pos = row_start[d] + atomicAdd(&cursor[d], 1);
        csr[pos] = make_int2(s, __float_as_int(src_norm[s]));
    }
}

// ---- fused propagation: out = 0.9*dn*sum(h[s]*w) + 0.1*h0; h stored fp16 ----
// one wave per dst node; 4 edges in flight (16 lanes x 8B fp16 each); prefetched csr.
__global__ __launch_bounds__(256) void agg_kernel(const __half* __restrict__ h,
                                                  const int2* __restrict__ csr,
                                                  const int* __restrict__ row_start,
                                                  const float* __restrict__ dst_norm,
                                                  const float* __restrict__ h0,
                                                  __half* __restrict__ out_h,
                                                  float* __restrict__ out_f,
                                                  int N, int last) {
    int node = blockIdx.x * 4 + (threadIdx.x >> 6);
    if (node >= N) return;
    int lane = threadIdx.x & 63;
    int g = lane >> 4;     // edge sub-group 0..3
    int fl = lane & 15;    // 8B (4 x fp16) feature chunk

    int beg = row_start[node];
    int end = row_start[node + 1];

    float4 acc = make_float4(0.f, 0.f, 0.f, 0.f);
    int i = beg + g;
    int2 sw = (i < end) ? csr[i] : make_int2(0, 0);
    while (i < end) {
        int inext = i + 4;
        int2 swn = (inext < end) ? csr[inext] : make_int2(0, 0);   // prefetch next
        float wgt = __int_as_float(sw.y);
        uint2 raw = ((const uint2*)h)[(size_t)sw.x * 16 + fl];
        __half2 p0 = *(__half2*)&raw.x;
        __half2 p1 = *(__half2*)&raw.y;
        float2 f0 = __half22float2(p0);
        float2 f1 = __half22float2(p1);
        acc.x = fmaf(f0.x, wgt, acc.x);
        acc.y = fmaf(f0.y, wgt, acc.y);
        acc.z = fmaf(f1.x, wgt, acc.z);
        acc.w = fmaf(f1.y, wgt, acc.w);
        sw = swn;
        i = inext;
    }
    // reduce the 4 edge sub-groups
    acc.x += __shfl_xor(acc.x, 16); acc.y += __shfl_xor(acc.y, 16);
    acc.z += __shfl_xor(acc.z, 16); acc.w += __shfl_xor(acc.w, 16);
    acc.x += __shfl_xor(acc.x, 32); acc.y += __shfl_xor(acc.y, 32);
    acc.z += __shfl_xor(acc.z, 32); acc.w += __shfl_xor(acc.w, 32);

    if (g == 0) {
        float dn = dst_norm[node];
        const float4* h0p = (const float4*)(h0 + (size_t)node * DOUT);
        // lane fl covers features fl*4..fl*4+3
        float4 h4 = h0p[fl];
        float4 o;
        o.x = fmaf(0.9f * dn, acc.x, 0.1f * h4.x);
        o.y = fmaf(0.9f * dn, acc.y, 0.1f * h4.y);
        o.z = fmaf(0.9f * dn, acc.z, 0.1f * h4.z);
        o.w = fmaf(0.9f * dn, acc.w, 0.1f * h4.w);
        if (last) {
            ((float4*)(out_f + (size_t)node * DOUT))[fl] = o;
        } else {
            __half2 q0 = __floats2half2_rn(o.x, o.y);
            __half2 q1 = __floats2half2_rn(o.z, o.w);
            uint2 packed;
            packed.x = *(unsigned*)&q0;
            packed.y = *(unsigned*)&q1;
            ((uint2*)(out_h + (size_t)node * DOUT))[fl] = packed;
        }
    }
}

extern "C" void kernel_launch(void* const* d_in, const int* in_sizes, int n_in,
                              void* d_out, int out_size, void* d_ws, size_t ws_size,
                              hipStream_t stream) {
    const float* feats = (const float*)d_in[0];
    const int*   src   = (const int*)d_in[1];
    const int*   dst   = (const int*)d_in[2];
    const float* W1    = (const float*)d_in[3];
    const float* b1    = (const float*)d_in[4];
    const float* W2    = (const float*)d_in[5];
    const float* b2    = (const float*)d_in[6];
    float* out = (float*)d_out;

    const int N = in_sizes[0] / DIN;   // 100000
    const int E = in_sizes[1];         // 1600000
    const int NCHUNK = (N + 255) / 256;

    char* w = (char*)d_ws;
    auto alloc = [&](size_t bytes) {
        char* p = w;
        w += (bytes + 255) & ~(size_t)255;
        return p;
    };
    float*  src_norm  = (float*)alloc((size_t)N * 4);
    float*  dst_norm  = (float*)alloc((size_t)N * 4);
    float*  h0        = (float*)alloc((size_t)N * DOUT * 4);
    __half* hA        = (__half*)alloc((size_t)N * DOUT * 2);
    __half* hB        = (__half*)alloc((size_t)N * DOUT * 2);
    int*    out_cnt   = (int*)alloc((size_t)N * 4);
    int*    in_cnt    = (int*)alloc((size_t)N * 4);
    int*    cursor    = (int*)alloc((size_t)N * 4);
    int*    row_start = (int*)alloc((size_t)(N + 1) * 4);
    int*    partials  = (int*)alloc((size_t)NCHUNK * 4);
    int2*   csr       = (int2*)alloc((size_t)E * 8);
    unsigned short* w1s = (unsigned short*)alloc((size_t)16 * 2 * 256 * 32 * 2);
    unsigned short* w2s = (unsigned short*)alloc((size_t)8 * 2 * 64 * 32 * 2);

    // ---- weight prep, then MLP first (keeps CSR hot in L3 for the agg loop) ----
    prep_w<<<(16 * 2 * 256 * 32 + 8 * 2 * 64 * 32 + 255) / 256, 256, 0, stream>>>(W1, W2, w1s, w2s);
    mlp_mfma<<<(N + 63) / 64, 256, 0, stream>>>(feats, w1s, w2s, b1, b2, h0, hA, N);

    // ---- CSR build ----
    hipMemsetAsync(out_cnt, 0, (size_t)N * 4, stream);
    hipMemsetAsync(in_cnt, 0, (size_t)N * 4, stream);
    hipMemsetAsync(cursor, 0, (size_t)N * 4, stream);
    deg_kernel<<<(E + 255) / 256, 256, 0, stream>>>(src, dst, out_cnt, in_cnt, E);
    norm_kernel<<<NCHUNK, 256, 0, stream>>>(out_cnt, in_cnt, src_norm, dst_norm, N);
    scan_chunk<<<NCHUNK, 256, 0, stream>>>(in_cnt, row_start, partials, N);
    scan_partials<<<1, 512, 0, stream>>>(partials, NCHUNK);
    scan_add<<<(N + 256) / 256, 256, 0, stream>>>(row_start, partials, N, E);
    fill_csr<<<(E + 255) / 256, 256, 0, stream>>>(src, dst, row_start, src_norm, cursor, csr, E);

    // ---- K = 10 propagation steps (fp16 h buffers; last iter writes fp32 out) ----
    const __half* cur = hA;
    for (int it = 0; it < 10; ++it) {
        int last = (it == 9) ? 1 : 0;
        __half* nh = (cur == hA) ? hB : hA;
        agg_kernel<<<(N + 3) / 4, 256, 0, stream>>>(cur, csr, row_start, dst_norm,
                                                    h0, nh, out, N, last);
        cur = nh;
    }
}

// Round 5
// 948.172 us; speedup vs baseline: 4.6457x; 1.0022x over previous
//
#include <hip/hip_runtime.h>
#include <hip/hip_fp16.h>

// APPNP: h = MLP(feats); then 10x { h = 0.9 * D^-1/2 A D^-1/2 h + 0.1 * h0 }
// N=100000, E=1600000, D_IN=512, D_HID=256, D_OUT=64
// Round 5: occupancy-first transposed-MFMA MLP (no A-LDS, 32KB LDS, 2x2 wave grid)
//          + fp16 propagation buffers + fused per-edge weights in CSR.

#define DIN 512
#define DHID 256
#define DOUT 64

typedef __attribute__((ext_vector_type(8))) short short8;
typedef __attribute__((ext_vector_type(4))) short short4v;
typedef __attribute__((ext_vector_type(4))) float f32x4;

__device__ __forceinline__ unsigned short f2bf(float f) {
    unsigned u = __float_as_uint(f);
    u += 0x7fffu + ((u >> 16) & 1u);
    return (unsigned short)(u >> 16);
}
__device__ __forceinline__ float bf2f(unsigned short h) {
    return __uint_as_float(((unsigned)h) << 16);
}
__device__ __forceinline__ void cvt8(const float4& f0, const float4& f1,
                                     short8& hi8, short8& lo8) {
    float fv[8] = {f0.x, f0.y, f0.z, f0.w, f1.x, f1.y, f1.z, f1.w};
#pragma unroll
    for (int e = 0; e < 8; ++e) {
        unsigned short h = f2bf(fv[e]);
        hi8[e] = (short)h;
        lo8[e] = (short)f2bf(fv[e] - bf2f(h));
    }
}

// ---- prep: W1/W2 -> transposed bf16 hi/lo staged layouts ----
// w1s: [kf=16][pl=2][n=256][k=32], value = W1[kf*32+k][n]
// w2s: [kf2=8][pl=2][n=64][k=32],  value = W2[kf2*32+k][n]
__global__ __launch_bounds__(256) void prep_w(const float* __restrict__ W1,
                                              const float* __restrict__ W2,
                                              unsigned short* __restrict__ w1s,
                                              unsigned short* __restrict__ w2s) {
    int i = blockIdx.x * 256 + threadIdx.x;
    const int NW1 = 16 * 2 * 256 * 32;
    if (i < NW1) {
        int e = i & 31;
        int n = (i >> 5) & 255;
        int pl = (i >> 13) & 1;
        int kf = i >> 14;
        float v = W1[(kf * 32 + e) * DHID + n];
        unsigned short hi = f2bf(v);
        w1s[i] = pl ? f2bf(v - bf2f(hi)) : hi;
    } else {
        int j = i - NW1;
        if (j < 8 * 2 * 64 * 32) {
            int e = j & 31;
            int n = (j >> 5) & 63;
            int pl = (j >> 11) & 1;
            int kf = j >> 12;
            float v = W2[(kf * 32 + e) * DOUT + n];
            unsigned short hi = f2bf(v);
            w2s[j] = pl ? f2bf(v - bf2f(hi)) : hi;
        }
    }
}

// ---- transposed MFMA MLP ----
// D^T = W^T . feats^T : A-frag = W (from prepped L2 layout), B-frag = feats rows
// loaded per-lane direct from global. C-frag: lane (c) = node row, reg = hid col.
// 256 thr = 4 waves in 2x2 grid: wave (wr=w>>1, wc=w&1) owns rows wr*32..+31 (2 rf)
// x hidcols wc*128..+127 (8 hf). LDS: 32KB hidden bf16 [64][256] XOR-swizzled;
// reused as 16KB fp32 out-stage for coalesced stores.
__global__ __launch_bounds__(256) void mlp_mfma(const float* __restrict__ feats,
                                                const unsigned short* __restrict__ w1s,
                                                const unsigned short* __restrict__ w2s,
                                                const float* __restrict__ b1,
                                                const float* __restrict__ b2,
                                                float* __restrict__ h0out,
                                                __half* __restrict__ hA, int N) {
    __shared__ char smem[32768];
    const int tid = threadIdx.x;
    const int w = tid >> 6, l = tid & 63, c = l & 15, g = l >> 4;
    const int wr = w >> 1, wc = w & 1;
    const int row0 = blockIdx.x * 64;

    f32x4 acc[2][8];
#pragma unroll
    for (int a = 0; a < 2; ++a)
#pragma unroll
        for (int b = 0; b < 8; ++b) acc[a][b] = (f32x4)0.0f;

    // ---- GEMM1: feats rows direct from global, W1 frags from L2 ----
    const int r0 = min(row0 + wr * 32 + c, N - 1);
    const int r1 = min(row0 + wr * 32 + 16 + c, N - 1);
    const float* ap0 = feats + (size_t)r0 * DIN + g * 8;
    const float* ap1 = feats + (size_t)r1 * DIN + g * 8;

    float4 f00 = *(const float4*)(ap0);
    float4 f01 = *(const float4*)(ap0 + 4);
    float4 f10 = *(const float4*)(ap1);
    float4 f11 = *(const float4*)(ap1 + 4);

    for (int kf = 0; kf < 16; ++kf) {
        short8 bh0, bl0, bh1, bl1;
        cvt8(f00, f01, bh0, bl0);
        cvt8(f10, f11, bh1, bl1);
        if (kf < 15) {   // prefetch next k-chunk
            f00 = *(const float4*)(ap0 + (kf + 1) * 32);
            f01 = *(const float4*)(ap0 + (kf + 1) * 32 + 4);
            f10 = *(const float4*)(ap1 + (kf + 1) * 32);
            f11 = *(const float4*)(ap1 + (kf + 1) * 32 + 4);
        }
        const unsigned short* wp = w1s + (size_t)kf * 16384;
#pragma unroll
        for (int hf = 0; hf < 8; ++hf) {
            int n = wc * 128 + hf * 16 + c;
            short8 wh = *(const short8*)(wp + n * 32 + g * 8);
            short8 wl = *(const short8*)(wp + (256 + n) * 32 + g * 8);
            acc[0][hf] = __builtin_amdgcn_mfma_f32_16x16x32_bf16(wh, bh0, acc[0][hf], 0, 0, 0);
            acc[1][hf] = __builtin_amdgcn_mfma_f32_16x16x32_bf16(wh, bh1, acc[1][hf], 0, 0, 0);
            acc[0][hf] = __builtin_amdgcn_mfma_f32_16x16x32_bf16(wl, bh0, acc[0][hf], 0, 0, 0);
            acc[1][hf] = __builtin_amdgcn_mfma_f32_16x16x32_bf16(wl, bh1, acc[1][hf], 0, 0, 0);
            acc[0][hf] = __builtin_amdgcn_mfma_f32_16x16x32_bf16(wh, bl0, acc[0][hf], 0, 0, 0);
            acc[1][hf] = __builtin_amdgcn_mfma_f32_16x16x32_bf16(wh, bl1, acc[1][hf], 0, 0, 0);
        }
    }

    // ---- bias + relu + hidden -> LDS (bf16, XOR-swizzled) ----
    // acc[rf][hf][r] = H[row = wr*32+rf*16+c][hidcol = wc*128+hf*16+g*4+r]
#pragma unroll
    for (int hf = 0; hf < 8; ++hf) {
        float4 bb = *(const float4*)(b1 + wc * 128 + hf * 16 + g * 4);
#pragma unroll
        for (int rf = 0; rf < 2; ++rf) {
            int row = wr * 32 + rf * 16 + c;
            short4v hv;
            hv[0] = (short)f2bf(fmaxf(acc[rf][hf][0] + bb.x, 0.0f));
            hv[1] = (short)f2bf(fmaxf(acc[rf][hf][1] + bb.y, 0.0f));
            hv[2] = (short)f2bf(fmaxf(acc[rf][hf][2] + bb.z, 0.0f));
            hv[3] = (short)f2bf(fmaxf(acc[rf][hf][3] + bb.w, 0.0f));
            int byt = (row * 512 + wc * 256 + hf * 32 + g * 8) ^ ((row & 7) << 4);
            *(short4v*)(smem + byt) = hv;
        }
    }
    __syncthreads();

    // ---- GEMM2: wave w owns rows w*16..+15; A=W2 frags (L2), B=hidden (LDS) ----
    f32x4 acc2[4];
#pragma unroll
    for (int q = 0; q < 4; ++q) acc2[q] = (f32x4)0.0f;
    const int myrow = w * 16 + c;
#pragma unroll
    for (int kf2 = 0; kf2 < 8; ++kf2) {
        int byt = (myrow * 512 + (kf2 * 32 + g * 8) * 2) ^ ((myrow & 7) << 4);
        short8 hb = *(const short8*)(smem + byt);
        const unsigned short* w2p = w2s + (size_t)kf2 * 4096;
#pragma unroll
        for (int of = 0; of < 4; ++of) {
            int n2 = of * 16 + c;
            short8 w2h = *(const short8*)(w2p + n2 * 32 + g * 8);
            short8 w2l = *(const short8*)(w2p + (64 + n2) * 32 + g * 8);
            acc2[of] = __builtin_amdgcn_mfma_f32_16x16x32_bf16(w2h, hb, acc2[of], 0, 0, 0);
            acc2[of] = __builtin_amdgcn_mfma_f32_16x16x32_bf16(w2l, hb, acc2[of], 0, 0, 0);
        }
    }
    __syncthreads();   // hidden reads done; reuse smem for out staging

    // ---- out-stage: acc2 -> LDS fp32 [64][64] swizzled ----
    // acc2[of][r] = out[row=myrow][outcol = of*16+g*4+r]
#pragma unroll
    for (int of = 0; of < 4; ++of) {
        float4 bb = *(const float4*)(b2 + of * 16 + g * 4);
        float4 v;
        v.x = acc2[of][0] + bb.x;
        v.y = acc2[of][1] + bb.y;
        v.z = acc2[of][2] + bb.z;
        v.w = acc2[of][3] + bb.w;
        int byt = (myrow * 256 + of * 64 + g * 16) ^ ((myrow & 7) << 4);
        *(float4*)(smem + byt) = v;
    }
    __syncthreads();

    // ---- coalesced final store: h0 (fp32) + hA (fp16) ----
    {
        int row = tid >> 2;          // 0..63
        int cq = tid & 3;            // 16-col quarter
        int gr = row0 + row;
        if (gr < N) {
#pragma unroll
            for (int j = 0; j < 4; ++j) {
                int lb = (row * 256 + cq * 64 + j * 16) ^ ((row & 7) << 4);
                float4 v = *(const float4*)(smem + lb);
                *(float4*)(h0out + (size_t)gr * DOUT + cq * 16 + j * 4) = v;
                __half2 q0 = __floats2half2_rn(v.x, v.y);
                __half2 q1 = __floats2half2_rn(v.z, v.w);
                uint2 packed;
                packed.x = *(unsigned*)&q0;
                packed.y = *(unsigned*)&q1;
                *(uint2*)(hA + (size_t)gr * DOUT + cq * 16 + j * 4) = packed;
            }
        }
    }
}

// ---- integer degree counts ----
__global__ __launch_bounds__(256) void deg_kernel(const int* __restrict__ src,
                                                  const int* __restrict__ dst,
                                                  int* __restrict__ out_cnt,
                                                  int* __restrict__ in_cnt, int E) {
    int e = blockIdx.x * 256 + threadIdx.x;
    if (e < E) {
        atomicAdd(&out_cnt[src[e]], 1);
        atomicAdd(&in_cnt[dst[e]], 1);
    }
}

// ---- counts -> deg^-1/2 norms ----
__global__ __launch_bounds__(256) void norm_kernel(const int* __restrict__ out_cnt,
                                                   const int* __restrict__ in_cnt,
                                                   float* __restrict__ src_norm,
                                                   float* __restrict__ dst_norm, int n) {
    int i = blockIdx.x * 256 + threadIdx.x;
    if (i < n) {
        src_norm[i] = rsqrtf((float)max(out_cnt[i], 1));
        dst_norm[i] = rsqrtf((float)max(in_cnt[i], 1));
    }
}

// ---- exclusive scan, stage 1 ----
__global__ __launch_bounds__(256) void scan_chunk(const int* __restrict__ cnt,
                                                  int* __restrict__ row_start,
                                                  int* __restrict__ partials, int n) {
    __shared__ int buf[256];
    int t = threadIdx.x;
    int i = blockIdx.x * 256 + t;
    int v = (i < n) ? cnt[i] : 0;
    buf[t] = v;
    __syncthreads();
    int val = v;
    for (int off = 1; off < 256; off <<= 1) {
        int add = (t >= off) ? buf[t - off] : 0;
        __syncthreads();
        val += add;
        buf[t] = val;
        __syncthreads();
    }
    if (i < n) row_start[i] = val - v;
    if (t == 255) partials[blockIdx.x] = val;
}

// ---- exclusive scan, stage 2 ----
__global__ __launch_bounds__(512) void scan_partials(int* __restrict__ partials, int nb) {
    __shared__ int buf[512];
    int t = threadIdx.x;
    int v = (t < nb) ? partials[t] : 0;
    buf[t] = v;
    __syncthreads();
    int val = v;
    for (int off = 1; off < 512; off <<= 1) {
        int add = (t >= off) ? buf[t - off] : 0;
        __syncthreads();
        val += add;
        buf[t] = val;
        __syncthreads();
    }
    int ex = (t == 0) ? 0 : buf[t - 1];
    __syncthreads();
    if (t < nb) partials[t] = ex;
}

// ---- exclusive scan, stage 3 ----
__global__ __launch_bounds__(256) void scan_add(int* __restrict__ row_start,
                                                const int* __restrict__ partials,
                                                int n, int E) {
    int i = blockIdx.x * 256 + threadIdx.x;
    if (i < n) row_start[i] += partials[blockIdx.x];
    if (i == n) row_start[n] = E;
}

// ---- CSR fill with fused per-edge weight: csr[pos] = (src, src_norm[src]) ----
__global__ __launch_bounds__(256) void fill_csr(const int* __restrict__ src,
                                                const int* __restrict__ dst,
                                                const int* __restrict__ row_start,
                                                const float* __restrict__ src_norm,
                                                int* __restrict__ cursor,
                                                int2* __restrict__ csr, int E) {
    int e = blockIdx.x * 256 + threadIdx.x;
    if (e < E) {
        int s = src[e];
        int d = dst[e];
        int pos = row_start[d] + atomicAdd(&cursor[d], 1);
        csr[pos] = make_int2(s, __float_as_int(src_norm[s]));
    }
}

// ---- fused propagation: out = 0.9*dn*sum(h[s]*w) + 0.1*h0; h stored fp16 ----
__global__ __launch_bounds__(256) void agg_kernel(const __half* __restrict__ h,
                                                  const int2* __restrict__ csr,
                                                  const int* __restrict__ row_start,
                                                  const float* __restrict__ dst_norm,
                                                  const float* __restrict__ h0,
                                                  __half* __restrict__ out_h,
                                                  float* __restrict__ out_f,
                                                  int N, int last) {
    int node = blockIdx.x * 4 + (threadIdx.x >> 6);
    if (node >= N) return;
    int lane = threadIdx.x & 63;
    int g = lane >> 4;
    int fl = lane & 15;

    int beg = row_start[node];
    int end = row_start[node + 1];

    float4 acc = make_float4(0.f, 0.f, 0.f, 0.f);
    int i = beg + g;
    int2 sw = (i < end) ? csr[i] : make_int2(0, 0);
    while (i < end) {
        int inext = i + 4;
        int2 swn = (inext < end) ? csr[inext] : make_int2(0, 0);
        float wgt = __int_as_float(sw.y);
        uint2 raw = ((const uint2*)h)[(size_t)sw.x * 16 + fl];
        __half2 p0 = *(__half2*)&raw.x;
        __half2 p1 = *(__half2*)&raw.y;
        float2 f0 = __half22float2(p0);
        float2 f1 = __half22float2(p1);
        acc.x = fmaf(f0.x, wgt, acc.x);
        acc.y = fmaf(f0.y, wgt, acc.y);
        acc.z = fmaf(f1.x, wgt, acc.z);
        acc.w = fmaf(f1.y, wgt, acc.w);
        sw = swn;
        i = inext;
    }
    acc.x += __shfl_xor(acc.x, 16); acc.y += __shfl_xor(acc.y, 16);
    acc.z += __shfl_xor(acc.z, 16); acc.w += __shfl_xor(acc.w, 16);
    acc.x += __shfl_xor(acc.x, 32); acc.y += __shfl_xor(acc.y, 32);
    acc.z += __shfl_xor(acc.z, 32); acc.w += __shfl_xor(acc.w, 32);

    if (g == 0) {
        float dn = dst_norm[node];
        const float4* h0p = (const float4*)(h0 + (size_t)node * DOUT);
        float4 h4 = h0p[fl];
        float4 o;
        o.x = fmaf(0.9f * dn, acc.x, 0.1f * h4.x);
        o.y = fmaf(0.9f * dn, acc.y, 0.1f * h4.y);
        o.z = fmaf(0.9f * dn, acc.z, 0.1f * h4.z);
        o.w = fmaf(0.9f * dn, acc.w, 0.1f * h4.w);
        if (last) {
            ((float4*)(out_f + (size_t)node * DOUT))[fl] = o;
        } else {
            __half2 q0 = __floats2half2_rn(o.x, o.y);
            __half2 q1 = __floats2half2_rn(o.z, o.w);
            uint2 packed;
            packed.x = *(unsigned*)&q0;
            packed.y = *(unsigned*)&q1;
            ((uint2*)(out_h + (size_t)node * DOUT))[fl] = packed;
        }
    }
}

extern "C" void kernel_launch(void* const* d_in, const int* in_sizes, int n_in,
                              void* d_out, int out_size, void* d_ws, size_t ws_size,
                              hipStream_t stream) {
    const float* feats = (const float*)d_in[0];
    const int*   src   = (const int*)d_in[1];
    const int*   dst   = (const int*)d_in[2];
    const float* W1    = (const float*)d_in[3];
    const float* b1    = (const float*)d_in[4];
    const float* W2    = (const float*)d_in[5];
    const float* b2    = (const float*)d_in[6];
    float* out = (float*)d_out;

    const int N = in_sizes[0] / DIN;   // 100000
    const int E = in_sizes[1];         // 1600000
    const int NCHUNK = (N + 255) / 256;

    char* w = (char*)d_ws;
    auto alloc = [&](size_t bytes) {
        char* p = w;
        w += (bytes + 255) & ~(size_t)255;
        return p;
    };
    float*  src_norm  = (float*)alloc((size_t)N * 4);
    float*  dst_norm  = (float*)alloc((size_t)N * 4);
    float*  h0        = (float*)alloc((size_t)N * DOUT * 4);
    __half* hA        = (__half*)alloc((size_t)N * DOUT * 2);
    __half* hB        = (__half*)alloc((size_t)N * DOUT * 2);
    int*    out_cnt   = (int*)alloc((size_t)N * 4);
    int*    in_cnt    = (int*)alloc((size_t)N * 4);
    int*    cursor    = (int*)alloc((size_t)N * 4);
    int*    row_start = (int*)alloc((size_t)(N + 1) * 4);
    int*    partials  = (int*)alloc((size_t)NCHUNK * 4);
    int2*   csr       = (int2*)alloc((size_t)E * 8);
    unsigned short* w1s = (unsigned short*)alloc((size_t)16 * 2 * 256 * 32 * 2);
    unsigned short* w2s = (unsigned short*)alloc((size_t)8 * 2 * 64 * 32 * 2);

    // ---- weight prep + MLP ----
    prep_w<<<(16 * 2 * 256 * 32 + 8 * 2 * 64 * 32 + 255) / 256, 256, 0, stream>>>(W1, W2, w1s, w2s);
    mlp_mfma<<<(N + 63) / 64, 256, 0, stream>>>(feats, w1s, w2s, b1, b2, h0, hA, N);

    // ---- CSR build ----
    hipMemsetAsync(out_cnt, 0, (size_t)N * 4, stream);
    hipMemsetAsync(in_cnt, 0, (size_t)N * 4, stream);
    hipMemsetAsync(cursor, 0, (size_t)N * 4, stream);
    deg_kernel<<<(E + 255) / 256, 256, 0, stream>>>(src, dst, out_cnt, in_cnt, E);
    norm_kernel<<<NCHUNK, 256, 0, stream>>>(out_cnt, in_cnt, src_norm, dst_norm, N);
    scan_chunk<<<NCHUNK, 256, 0, stream>>>(in_cnt, row_start, partials, N);
    scan_partials<<<1, 512, 0, stream>>>(partials, NCHUNK);
    scan_add<<<(N + 256) / 256, 256, 0, stream>>>(row_start, partials, N, E);
    fill_csr<<<(E + 255) / 256, 256, 0, stream>>>(src, dst, row_start, src_norm, cursor, csr, E);

    // ---- K = 10 propagation steps ----
    const __half* cur = hA;
    for (int it = 0; it < 10; ++it) {
        int last = (it == 9) ? 1 : 0;
        __half* nh = (cur == hA) ? hB : hA;
        agg_kernel<<<(N + 3) / 4, 256, 0, stream>>>(cur, csr, row_start, dst_norm,
                                                    h0, nh, out, N, last);
        cur = nh;
    }
}